// Round 1
// baseline (201.829 us; speedup 1.0000x reference)
//
#include <hip/hip_runtime.h>
#include <math.h>

#define CCH 8
#define BLK 256

__global__ __launch_bounds__(BLK) void stats_dot_kernel(
    const float* __restrict__ x,   // [B, T, C]
    const float* __restrict__ W,   // [1, 5*C]
    const float* __restrict__ bias,// [1]
    float* __restrict__ out,       // [B]
    int T)
{
    const int b   = blockIdx.x;
    const int tid = threadIdx.x;
    const float* xb = x + (size_t)b * (size_t)T * CCH;

    float s1[CCH], s2[CCH], s3[CCH], mx[CCH];
    int   cnt[CCH];
#pragma unroll
    for (int c = 0; c < CCH; ++c) {
        s1[c] = 0.f; s2[c] = 0.f; s3[c] = 0.f;
        mx[c] = -INFINITY; cnt[c] = 0;
    }

    // Each thread covers t = tid, tid+BLK, ... ; reads full 8-channel row (32B)
    for (int t = tid; t < T; t += BLK) {
        const float4* p = (const float4*)(xb + (size_t)t * CCH);
        float4 v0 = p[0];
        float4 v1 = p[1];
        float v[8] = {v0.x, v0.y, v0.z, v0.w, v1.x, v1.y, v1.z, v1.w};
#pragma unroll
        for (int c = 0; c < CCH; ++c) {
            float xv = v[c];
            s1[c] += xv;
            s2[c]  = fmaf(xv, xv, s2[c]);
            s3[c]  = fmaf(xv * xv, xv, s3[c]);
            mx[c]  = fmaxf(mx[c], xv);
            cnt[c] += (xv > 0.f) ? 1 : 0;
        }
    }

    // ---- wave (64-lane) reduction; sums promoted to double ----
    double d1[CCH], d2[CCH], d3[CCH];
#pragma unroll
    for (int c = 0; c < CCH; ++c) { d1[c] = s1[c]; d2[c] = s2[c]; d3[c] = s3[c]; }

#pragma unroll
    for (int off = 32; off >= 1; off >>= 1) {
#pragma unroll
        for (int c = 0; c < CCH; ++c) {
            d1[c] += __shfl_down(d1[c], off);
            d2[c] += __shfl_down(d2[c], off);
            d3[c] += __shfl_down(d3[c], off);
            mx[c]  = fmaxf(mx[c], __shfl_down(mx[c], off));
            cnt[c] += __shfl_down(cnt[c], off);
        }
    }

    // ---- cross-wave reduction via LDS (4 waves) ----
    __shared__ double sh1[4][CCH], sh2[4][CCH], sh3[4][CCH];
    __shared__ float  shm[4][CCH];
    __shared__ int    shc[4][CCH];

    const int wave = tid >> 6;
    const int lane = tid & 63;
    if (lane == 0) {
#pragma unroll
        for (int c = 0; c < CCH; ++c) {
            sh1[wave][c] = d1[c];
            sh2[wave][c] = d2[c];
            sh3[wave][c] = d3[c];
            shm[wave][c] = mx[c];
            shc[wave][c] = cnt[c];
        }
    }
    __syncthreads();

    if (tid == 0) {
        const double Td = (double)T;
        float result = bias[0];
#pragma unroll
        for (int c = 0; c < CCH; ++c) {
            double S1 = 0.0, S2 = 0.0, S3 = 0.0;
            float  M  = -INFINITY;
            int    CT = 0;
#pragma unroll
            for (int w = 0; w < 4; ++w) {
                S1 += sh1[w][c]; S2 += sh2[w][c]; S3 += sh3[w][c];
                M = fmaxf(M, shm[w][c]); CT += shc[w][c];
            }
            double m1  = S1 / Td;
            double var = (S2 - S1 * m1) / (Td - 1.0);
            if (var < 0.0) var = 0.0;
            double sd  = sqrt(var);
            double m2  = S2 / Td;
            double m3  = S3 / Td;
            double c3  = m3 - 3.0 * m1 * m2 + 2.0 * m1 * m1 * m1;
            double sde = sd + 1e-8;
            double skew = c3 / (sde * sde * sde);
            // feature order per channel: [max, mean, cnt, std, skew]
            result += M          * W[c * 5 + 0];
            result += (float)m1  * W[c * 5 + 1];
            result += (float)CT  * W[c * 5 + 2];
            result += (float)sd  * W[c * 5 + 3];
            result += (float)skew* W[c * 5 + 4];
        }
        out[b] = result;
    }
}

extern "C" void kernel_launch(void* const* d_in, const int* in_sizes, int n_in,
                              void* d_out, int out_size, void* d_ws, size_t ws_size,
                              hipStream_t stream) {
    const float* x  = (const float*)d_in[0];
    const float* W  = (const float*)d_in[1];
    const float* bi = (const float*)d_in[2];
    float* out = (float*)d_out;

    const int B = out_size;                       // 2048
    const int T = in_sizes[0] / (B * CCH);        // 16384

    stats_dot_kernel<<<B, BLK, 0, stream>>>(x, W, bi, out, T);
}

// Round 2
// 163.800 us; speedup vs baseline: 1.2322x; 1.2322x over previous
//
#include <hip/hip_runtime.h>
#include <math.h>

#define CCH 8
#define BLK 256

typedef float f32x4 __attribute__((ext_vector_type(4)));

__global__ __launch_bounds__(BLK, 8) void stats_dot_kernel(
    const float* __restrict__ x,   // [B, T, C]
    const float* __restrict__ W,   // [1, 5*C]
    const float* __restrict__ bias,// [1]
    float* __restrict__ out,       // [B]
    int T)
{
    const int b   = blockIdx.x;
    const int tid = threadIdx.x;
    const f32x4* xb = (const f32x4*)(x + (size_t)b * (size_t)T * CCH);
    const int nvec = T * 2;        // float4 count per row

    // Each thread handles 4 channels: even tid -> ch0-3, odd tid -> ch4-7
    float s1[4], s2[4], s3[4], mx[4];
    int   cnt[4];
#pragma unroll
    for (int c = 0; c < 4; ++c) {
        s1[c] = 0.f; s2[c] = 0.f; s3[c] = 0.f;
        mx[c] = -INFINITY; cnt[c] = 0;
    }

    // j parity == tid parity (BLK even), so channel group is constant per thread.
    // One dense float4 per thread per step: wave = 1024B contiguous / instruction.
#pragma unroll 4
    for (int j = tid; j < nvec; j += BLK) {
        f32x4 v = __builtin_nontemporal_load(xb + j);
#pragma unroll
        for (int c = 0; c < 4; ++c) {
            float xv = v[c];
            s1[c] += xv;
            s2[c]  = fmaf(xv, xv, s2[c]);
            s3[c]  = fmaf(xv * xv, xv, s3[c]);
            mx[c]  = fmaxf(mx[c], xv);
            cnt[c] += (xv > 0.f) ? 1 : 0;
        }
    }

    // ---- wave reduction, parity-preserving (offsets 32..2) ----
    // After this, lane 0 holds even-lane (ch0-3) sums, lane 1 odd-lane (ch4-7).
#pragma unroll
    for (int off = 32; off >= 2; off >>= 1) {
#pragma unroll
        for (int c = 0; c < 4; ++c) {
            s1[c] += __shfl_down(s1[c], off);
            s2[c] += __shfl_down(s2[c], off);
            s3[c] += __shfl_down(s3[c], off);
            mx[c]  = fmaxf(mx[c], __shfl_down(mx[c], off));
            cnt[c] += __shfl_down(cnt[c], off);
        }
    }

    // ---- cross-wave combine via LDS ----
    __shared__ float sh[4][2][4][5];   // [wave][group][ch][stat]
    const int wave = tid >> 6;
    const int lane = tid & 63;
    if (lane < 2) {
        const int g = lane;            // lane0 = even tids = ch0-3
#pragma unroll
        for (int c = 0; c < 4; ++c) {
            sh[wave][g][c][0] = mx[c];
            sh[wave][g][c][1] = s1[c];
            sh[wave][g][c][2] = (float)cnt[c];
            sh[wave][g][c][3] = s2[c];
            sh[wave][g][c][4] = s3[c];
        }
    }
    __syncthreads();

    if (tid == 0) {
        const double Td = (double)T;
        float result = bias[0];
#pragma unroll
        for (int ch = 0; ch < CCH; ++ch) {
            const int g = ch >> 2, c = ch & 3;
            double S1 = 0.0, S2 = 0.0, S3 = 0.0, CT = 0.0;
            float  M  = -INFINITY;
#pragma unroll
            for (int w = 0; w < 4; ++w) {
                M   = fmaxf(M, sh[w][g][c][0]);
                S1 += (double)sh[w][g][c][1];
                CT += (double)sh[w][g][c][2];
                S2 += (double)sh[w][g][c][3];
                S3 += (double)sh[w][g][c][4];
            }
            double m1  = S1 / Td;
            double var = (S2 - S1 * m1) / (Td - 1.0);
            if (var < 0.0) var = 0.0;
            double sd  = sqrt(var);
            double m2  = S2 / Td;
            double m3  = S3 / Td;
            double c3  = m3 - 3.0 * m1 * m2 + 2.0 * m1 * m1 * m1;
            double sde = sd + 1e-8;
            double skew = c3 / (sde * sde * sde);
            // feature order per channel: [max, mean, cnt, std, skew]
            result += M           * W[ch * 5 + 0];
            result += (float)m1   * W[ch * 5 + 1];
            result += (float)CT   * W[ch * 5 + 2];
            result += (float)sd   * W[ch * 5 + 3];
            result += (float)skew * W[ch * 5 + 4];
        }
        out[b] = result;
    }
}

extern "C" void kernel_launch(void* const* d_in, const int* in_sizes, int n_in,
                              void* d_out, int out_size, void* d_ws, size_t ws_size,
                              hipStream_t stream) {
    const float* x  = (const float*)d_in[0];
    const float* W  = (const float*)d_in[1];
    const float* bi = (const float*)d_in[2];
    float* out = (float*)d_out;

    const int B = out_size;                       // 2048
    const int T = in_sizes[0] / (B * CCH);        // 16384

    stats_dot_kernel<<<B, BLK, 0, stream>>>(x, W, bi, out, T);
}